// Round 1
// baseline (1141.486 us; speedup 1.0000x reference)
//
#include <hip/hip_runtime.h>
#include <hip/hip_bf16.h>
#include <math.h>

// MoEHeadAdapter: N=65536, D=256, E=4, H=512, K=2, EMB=512.
// Dense-expert compute (all 4 experts scaled by sparse gates) == reference einsum.
// Dtype-agnostic: k_sniff detects fp32 vs bf16 input encoding at runtime.
// ws: [0,4) flag | [4096, +1MB) W1t [4][512][256] bf16 | +1MB W2t [4][256][512] |
//     +2MB Wpt [512][256].  Total < 2.3 MB (no large intermediates).
//
// R1: 64-token blocks / 256 threads / LDS 52224 B -> 3 blocks/CU (was 128/512/108.5KB
//     -> 1 block/CU). Inter-block TLP hides barriers + gelu VALU under MFMA.
//     erff -> branch-free tanh-gelu (~10 VALU ops vs ~40 divergent).

typedef __attribute__((ext_vector_type(4))) float f32x4;
typedef __attribute__((ext_vector_type(8))) short bf16x8;

#define MFMA16(a, b, c) __builtin_amdgcn_mfma_f32_16x16x32_bf16((a), (b), (c), 0, 0, 0)

__device__ __forceinline__ float bf2f(__hip_bfloat16 v) { return __bfloat162float(v); }

// tanh-form gelu: max |err| vs exact erf-gelu ~2e-4 (negligible vs bf16 rounding of H).
__device__ __forceinline__ float gelu_f(float v) {
    float t = 0.7978845608028654f * v * (1.f + 0.044715f * v * v);
    float e = __expf(2.f * t);                       // e^{2t}; inf/0 limits give +/-1 tanh
    float th = 1.f - 2.f * __builtin_amdgcn_rcpf(e + 1.f);
    return 0.5f * v * (1.f + th);
}

// ---------------- K-1: dtype sniff ----------------
__global__ void k_sniff(const unsigned short* __restrict__ xr, int* __restrict__ flag) {
    int lane = threadIdx.x;
    int cnt = 0;
#pragma unroll
    for (int j = 0; j < 4; ++j) {
        unsigned short v = xr[2 * (lane * 4 + j)];
        int e = (v >> 7) & 0xFF;
        cnt += (e >= 97 && e <= 157) ? 1 : 0;
    }
#pragma unroll
    for (int off = 32; off; off >>= 1) cnt += __shfl_down(cnt, off);
    if (lane == 0) flag[0] = (cnt < 192) ? 1 : 0;  // 1 = fp32 mode
}

// ---------------- K0: weight transposes -> bf16 ----------------
__global__ void k_prep(const void* __restrict__ w1,   // [4][256][512]
                       const void* __restrict__ w2,   // [4][512][256]
                       const void* __restrict__ wp,   // [256][512]
                       const int* __restrict__ flag,
                       __hip_bfloat16* __restrict__ w1t,   // [4][512][256]
                       __hip_bfloat16* __restrict__ w2t,   // [4][256][512]
                       __hip_bfloat16* __restrict__ wpt) { // [512][256]
    int i = blockIdx.x * 256 + threadIdx.x;  // [0, 524288)
    const bool f32m = (flag[0] != 0);
    {   // w1t[e][h][d] = w1[e][d][h]
        int e = i >> 17, j = i & 131071;
        int h = j >> 8, d = j & 255;
        int s = (e << 17) + (d << 9) + h;
        w1t[i] = f32m ? __float2bfloat16(((const float*)w1)[s]) : ((const __hip_bfloat16*)w1)[s];
    }
    {   // w2t[e][d][h] = w2[e][h][d]
        int e = i >> 17, j = i & 131071;
        int d = j >> 9, h = j & 511;
        int s = (e << 17) + (h << 8) + d;
        w2t[i] = f32m ? __float2bfloat16(((const float*)w2)[s]) : ((const __hip_bfloat16*)w2)[s];
    }
    if (i < 131072) {  // wpt[n][d] = wp[d][n]
        int n = i >> 8, d = i & 255;
        int s = (d << 9) + n;
        wpt[i] = f32m ? __float2bfloat16(((const float*)wp)[s]) : ((const __hip_bfloat16*)wp)[s];
    }
}

// ---------------- fused: gating + dense expert FFN + out projection ----------------
// grid 1024 x 256 threads; block = 64 tokens; 4 waves (wr = wv&1 rows, wc = wv>>1 cols).
// LDS layout (52224 B total -> 3 blocks/CU):
//   Xs [64][264] bf16  @0      (33792)
//   Hs [64][136] bf16  @33792  (17408)   } wgs [4][256] f32 aliases Hs (dead after gating)
//   gate_s [64][4] f32 @51200  (1024)
__global__ __launch_bounds__(256, 3) void k_moe(
    const void* __restrict__ xin,     // [65536][256]
    const void* __restrict__ wg,      // [256][4]
    const __hip_bfloat16* __restrict__ w1t,   // [4][512][256]
    const __hip_bfloat16* __restrict__ w2t,   // [4][256][512]
    const __hip_bfloat16* __restrict__ wpt,   // [512][256]
    const void* __restrict__ bp,      // [512]
    const int* __restrict__ flag,
    void* __restrict__ outp) {        // [65536][512]
    extern __shared__ char smem[];
    __hip_bfloat16* Xs = (__hip_bfloat16*)smem;             // stride 264
    __hip_bfloat16* Hs = (__hip_bfloat16*)(smem + 33792);   // stride 136
    float* gate_s = (float*)(smem + 51200);                 // [64][4]
    float* wgs = (float*)(smem + 33792);                    // aliases Hs region

    const int tid = threadIdx.x;
    const int m0 = blockIdx.x * 64;
    const bool f32m = (flag[0] != 0);

    // ---- stage X tile as bf16 ----
    if (!f32m) {
        const uint4* xg = (const uint4*)((const __hip_bfloat16*)xin + (size_t)m0 * 256);
#pragma unroll
        for (int i = 0; i < 8; ++i) {
            int f = tid + 256 * i;          // uint4 index over [64][32]
            int r = f >> 5, c = f & 31;
            *(uint4*)&Xs[r * 264 + c * 8] = xg[f];
        }
    } else {
        const float4* xg = (const float4*)((const float*)xin + (size_t)m0 * 256);
#pragma unroll
        for (int i = 0; i < 8; ++i) {
            int f = tid + 256 * i;
            int r = f >> 5, c = f & 31;
            float4 a = xg[2 * f], b = xg[2 * f + 1];
            __hip_bfloat16* d = &Xs[r * 264 + c * 8];
            d[0] = __float2bfloat16(a.x); d[1] = __float2bfloat16(a.y);
            d[2] = __float2bfloat16(a.z); d[3] = __float2bfloat16(a.w);
            d[4] = __float2bfloat16(b.x); d[5] = __float2bfloat16(b.y);
            d[6] = __float2bfloat16(b.z); d[7] = __float2bfloat16(b.w);
        }
    }
    {  // w_gate transposed to LDS as f32: wgs[e][d]  (aliases Hs -- dead after gating)
#pragma unroll
        for (int e = 0; e < 4; ++e)
            wgs[e * 256 + tid] = f32m ? ((const float*)wg)[tid * 4 + e]
                                      : bf2f(((const __hip_bfloat16*)wg)[tid * 4 + e]);
    }
    __syncthreads();

    // ---- gating logits at FULL input precision (top-k is discrete!) ----
    {
        int tok = tid >> 2, e = tid & 3;
        float acc = 0.f;
        if (f32m) {
            const float4* xrow = (const float4*)((const float*)xin + (size_t)(m0 + tok) * 256);
            const float* wrow = &wgs[e * 256];
#pragma unroll 8
            for (int q = 0; q < 64; ++q) {
                float4 xv = xrow[q];
                acc += xv.x * wrow[q * 4] + xv.y * wrow[q * 4 + 1]
                     + xv.z * wrow[q * 4 + 2] + xv.w * wrow[q * 4 + 3];
            }
        } else {
            const float* wrow = &wgs[e * 256];
#pragma unroll 4
            for (int d8 = 0; d8 < 32; ++d8) {
                bf16x8 xv = *(const bf16x8*)&Xs[tok * 264 + d8 * 8];
#pragma unroll
                for (int j = 0; j < 8; ++j) {
                    union { unsigned u; float f; } c;
                    c.u = ((unsigned)(unsigned short)xv[j]) << 16;
                    acc += c.f * wrow[d8 * 8 + j];
                }
            }
        }
        gate_s[tok * 4 + e] = acc;  // logits for now
    }
    __syncthreads();
    // top-2 + softmax (jax.lax.top_k ties -> lowest index; strict > keeps first)
    if (tid < 64) {
        float l[4];
#pragma unroll
        for (int e = 0; e < 4; ++e) l[e] = gate_s[tid * 4 + e];
        int i0 = 0; float v0 = l[0];
#pragma unroll
        for (int e = 1; e < 4; ++e)
            if (l[e] > v0) { v0 = l[e]; i0 = e; }
        int i1 = -1; float v1 = -1e30f;
#pragma unroll
        for (int e = 0; e < 4; ++e)
            if (e != i0 && l[e] > v1) { v1 = l[e]; i1 = e; }
        float t = __expf(v1 - v0);
        float g0 = 1.f / (1.f + t);
        float g1 = t * g0;
#pragma unroll
        for (int e = 0; e < 4; ++e) gate_s[tid * 4 + e] = 0.f;
        gate_s[tid * 4 + i0] = g0;
        gate_s[tid * 4 + i1] = g1;
    }
    __syncthreads();

    const int lane = tid & 63;
    const int wv = tid >> 6;       // 4 waves
    const int wr = wv & 1;         // rows 32*wr..+32
    const int wc = wv >> 1;        // col group 0/1
    const int lm = lane & 15, quad = lane >> 4;

    f32x4 Yacc[2][8];  // Y wave-tile [32][128]
#pragma unroll
    for (int a = 0; a < 2; ++a)
#pragma unroll
        for (int b = 0; b < 8; ++b) Yacc[a][b] = (f32x4){0.f, 0.f, 0.f, 0.f};

#pragma unroll 1
    for (int e = 0; e < 4; ++e) {
        const __hip_bfloat16* w1e = w1t + (e << 17);
        const __hip_bfloat16* w2e = w2t + (e << 17);
#pragma unroll 1
        for (int hc = 0; hc < 512; hc += 128) {
            // Phase A: Hc[64][128] = X @ W1e[:, hc:hc+128]; wave sub-tile [32][64]
            f32x4 Hacc[2][4];
#pragma unroll
            for (int a = 0; a < 2; ++a)
#pragma unroll
                for (int b = 0; b < 4; ++b) Hacc[a][b] = (f32x4){0.f, 0.f, 0.f, 0.f};
#pragma unroll
            for (int k = 0; k < 256; k += 32) {
                bf16x8 af[2];
#pragma unroll
                for (int mt = 0; mt < 2; ++mt)
                    af[mt] = *(const bf16x8*)&Xs[(32 * wr + 16 * mt + lm) * 264 + k + quad * 8];
#pragma unroll
                for (int nt = 0; nt < 4; ++nt) {
                    int h = hc + 64 * wc + 16 * nt + lm;
                    bf16x8 bfr = *(const bf16x8*)&w1e[(h << 8) + k + quad * 8];
                    Hacc[0][nt] = MFMA16(af[0], bfr, Hacc[0][nt]);
                    Hacc[1][nt] = MFMA16(af[1], bfr, Hacc[1][nt]);
                }
            }
            // gelu (tanh form) + gate scale -> Hs (bf16)
#pragma unroll
            for (int mt = 0; mt < 2; ++mt)
#pragma unroll
                for (int nt = 0; nt < 4; ++nt)
#pragma unroll
                    for (int r = 0; r < 4; ++r) {
                        int row = 32 * wr + 16 * mt + quad * 4 + r;
                        int col = 64 * wc + 16 * nt + lm;
                        float g = gelu_f(Hacc[mt][nt][r]);
                        g *= gate_s[row * 4 + e];
                        Hs[row * 136 + col] = __float2bfloat16(g);
                    }
            __syncthreads();
            // Phase B: Y += Hc @ W2e[hc:hc+128, :]
#pragma unroll
            for (int kk = 0; kk < 128; kk += 32) {
                bf16x8 af[2];
#pragma unroll
                for (int mt = 0; mt < 2; ++mt)
                    af[mt] = *(const bf16x8*)&Hs[(32 * wr + 16 * mt + lm) * 136 + kk + quad * 8];
#pragma unroll
                for (int nt = 0; nt < 8; ++nt) {
                    int d = 128 * wc + 16 * nt + lm;
                    bf16x8 bfr = *(const bf16x8*)&w2e[(d << 9) + hc + kk + quad * 8];
                    Yacc[0][nt] = MFMA16(af[0], bfr, Yacc[0][nt]);
                    Yacc[1][nt] = MFMA16(af[1], bfr, Yacc[1][nt]);
                }
            }
            __syncthreads();
        }
    }

    // ---- Y -> LDS (reuse Xs region; all waves past their last Xs read) ----
#pragma unroll
    for (int mt = 0; mt < 2; ++mt)
#pragma unroll
        for (int nt = 0; nt < 8; ++nt)
#pragma unroll
            for (int r = 0; r < 4; ++r) {
                int row = 32 * wr + 16 * mt + quad * 4 + r;
                int col = 128 * wc + 16 * nt + lm;
                Xs[row * 264 + col] = __float2bfloat16(Yacc[mt][nt][r]);
            }
    __syncthreads();

    // ---- projection: OUT[64][512] = Y @ Wproj + b ----
#pragma unroll 1
    for (int p = 0; p < 2; ++p) {
        int n0 = 128 * (2 * wc + p);
        f32x4 acc[2][8];
#pragma unroll
        for (int a = 0; a < 2; ++a)
#pragma unroll
            for (int b = 0; b < 8; ++b) acc[a][b] = (f32x4){0.f, 0.f, 0.f, 0.f};
#pragma unroll
        for (int k = 0; k < 256; k += 32) {
            bf16x8 af[2];
#pragma unroll
            for (int mt = 0; mt < 2; ++mt)
                af[mt] = *(const bf16x8*)&Xs[(32 * wr + 16 * mt + lm) * 264 + k + quad * 8];
#pragma unroll
            for (int nt = 0; nt < 8; ++nt) {
                int n = n0 + 16 * nt + lm;
                bf16x8 bfr = *(const bf16x8*)&wpt[(n << 8) + k + quad * 8];
                acc[0][nt] = MFMA16(af[0], bfr, acc[0][nt]);
                acc[1][nt] = MFMA16(af[1], bfr, acc[1][nt]);
            }
        }
#pragma unroll
        for (int nt = 0; nt < 8; ++nt) {
            int col = n0 + 16 * nt + lm;
            float bv = f32m ? ((const float*)bp)[col] : bf2f(((const __hip_bfloat16*)bp)[col]);
#pragma unroll
            for (int mt = 0; mt < 2; ++mt)
#pragma unroll
                for (int r = 0; r < 4; ++r) {
                    int row = m0 + 32 * wr + 16 * mt + quad * 4 + r;
                    float v = acc[mt][nt][r] + bv;
                    if (f32m) ((float*)outp)[(size_t)row * 512 + col] = v;
                    else ((__hip_bfloat16*)outp)[(size_t)row * 512 + col] = __float2bfloat16(v);
                }
        }
    }
}

extern "C" void kernel_launch(void* const* d_in, const int* in_sizes, int n_in,
                              void* d_out, int out_size, void* d_ws, size_t ws_size,
                              hipStream_t stream) {
    const void* x  = d_in[0];
    const void* wg = d_in[1];
    const void* w1 = d_in[2];
    const void* w2 = d_in[3];
    const void* wp = d_in[4];
    const void* bp = d_in[5];

    char* ws = (char*)d_ws;
    int* flag = (int*)(ws + 0);
    __hip_bfloat16* w1t = (__hip_bfloat16*)(ws + 4096);
    __hip_bfloat16* w2t = (__hip_bfloat16*)(ws + 4096 + (1u << 20));
    __hip_bfloat16* wpt = (__hip_bfloat16*)(ws + 4096 + (2u << 20));

    k_sniff<<<1, 64, 0, stream>>>((const unsigned short*)x, flag);
    k_prep<<<2048, 256, 0, stream>>>(w1, w2, wp, flag, w1t, w2t, wpt);
    k_moe<<<1024, 256, 52224, stream>>>(x, wg, w1t, w2t, wpt, bp, flag, d_out);
}

// Round 2
// 867.749 us; speedup vs baseline: 1.3155x; 1.3155x over previous
//
#include <hip/hip_runtime.h>
#include <hip/hip_bf16.h>
#include <math.h>

// MoEHeadAdapter: N=65536, D=256, E=4, H=512, K=2, EMB=512.
// Dense-expert compute (all 4 experts scaled by sparse gates) == reference einsum.
// Dtype-agnostic: k_sniff detects fp32 vs bf16 input encoding at runtime.
// ws: [0,4) flag | [4096, +1MB) W1t [4][512][256] bf16 | +1MB W2t [4][256][512] |
//     +2MB Wpt [512][256].  Total < 2.3 MB (no large intermediates).
//
// R1: 64-token blocks / 256 threads / LDS 52224 B; tanh-gelu.
// R2: __launch_bounds__(256,3) in R1 capped unified regs at ~168 (split 84 arch/84
//     accum) < accumulator peak 96 (Yacc 64 + Hacc 32) -> accumulator scratch spill
//     (WRITE_SIZE 247MB -> 1.44GB, VALUBusy 19 -> 9.7).  Relax to (256,2): budget
//     256 regs, demand ~140, no spill; LDS still allows 3 blocks/CU if alloc <= 168.

typedef __attribute__((ext_vector_type(4))) float f32x4;
typedef __attribute__((ext_vector_type(8))) short bf16x8;

#define MFMA16(a, b, c) __builtin_amdgcn_mfma_f32_16x16x32_bf16((a), (b), (c), 0, 0, 0)

__device__ __forceinline__ float bf2f(__hip_bfloat16 v) { return __bfloat162float(v); }

// tanh-form gelu: max |err| vs exact erf-gelu ~2e-4 (negligible vs bf16 rounding of H).
__device__ __forceinline__ float gelu_f(float v) {
    float t = 0.7978845608028654f * v * (1.f + 0.044715f * v * v);
    float e = __expf(2.f * t);                       // e^{2t}; inf/0 limits give +/-1 tanh
    float th = 1.f - 2.f * __builtin_amdgcn_rcpf(e + 1.f);
    return 0.5f * v * (1.f + th);
}

// ---------------- K-1: dtype sniff ----------------
__global__ void k_sniff(const unsigned short* __restrict__ xr, int* __restrict__ flag) {
    int lane = threadIdx.x;
    int cnt = 0;
#pragma unroll
    for (int j = 0; j < 4; ++j) {
        unsigned short v = xr[2 * (lane * 4 + j)];
        int e = (v >> 7) & 0xFF;
        cnt += (e >= 97 && e <= 157) ? 1 : 0;
    }
#pragma unroll
    for (int off = 32; off; off >>= 1) cnt += __shfl_down(cnt, off);
    if (lane == 0) flag[0] = (cnt < 192) ? 1 : 0;  // 1 = fp32 mode
}

// ---------------- K0: weight transposes -> bf16 ----------------
__global__ void k_prep(const void* __restrict__ w1,   // [4][256][512]
                       const void* __restrict__ w2,   // [4][512][256]
                       const void* __restrict__ wp,   // [256][512]
                       const int* __restrict__ flag,
                       __hip_bfloat16* __restrict__ w1t,   // [4][512][256]
                       __hip_bfloat16* __restrict__ w2t,   // [4][256][512]
                       __hip_bfloat16* __restrict__ wpt) { // [512][256]
    int i = blockIdx.x * 256 + threadIdx.x;  // [0, 524288)
    const bool f32m = (flag[0] != 0);
    {   // w1t[e][h][d] = w1[e][d][h]
        int e = i >> 17, j = i & 131071;
        int h = j >> 8, d = j & 255;
        int s = (e << 17) + (d << 9) + h;
        w1t[i] = f32m ? __float2bfloat16(((const float*)w1)[s]) : ((const __hip_bfloat16*)w1)[s];
    }
    {   // w2t[e][d][h] = w2[e][h][d]
        int e = i >> 17, j = i & 131071;
        int d = j >> 9, h = j & 511;
        int s = (e << 17) + (h << 8) + d;
        w2t[i] = f32m ? __float2bfloat16(((const float*)w2)[s]) : ((const __hip_bfloat16*)w2)[s];
    }
    if (i < 131072) {  // wpt[n][d] = wp[d][n]
        int n = i >> 8, d = i & 255;
        int s = (d << 9) + n;
        wpt[i] = f32m ? __float2bfloat16(((const float*)wp)[s]) : ((const __hip_bfloat16*)wp)[s];
    }
}

// ---------------- fused: gating + dense expert FFN + out projection ----------------
// grid 1024 x 256 threads; block = 64 tokens; 4 waves (wr = wv&1 rows, wc = wv>>1 cols).
// LDS layout (52224 B total -> 3 blocks/CU by LDS):
//   Xs [64][264] bf16  @0      (33792)
//   Hs [64][136] bf16  @33792  (17408)   } wgs [4][256] f32 aliases Hs (dead after gating)
//   gate_s [64][4] f32 @51200  (1024)
__global__ __launch_bounds__(256, 2) void k_moe(
    const void* __restrict__ xin,     // [65536][256]
    const void* __restrict__ wg,      // [256][4]
    const __hip_bfloat16* __restrict__ w1t,   // [4][512][256]
    const __hip_bfloat16* __restrict__ w2t,   // [4][256][512]
    const __hip_bfloat16* __restrict__ wpt,   // [512][256]
    const void* __restrict__ bp,      // [512]
    const int* __restrict__ flag,
    void* __restrict__ outp) {        // [65536][512]
    extern __shared__ char smem[];
    __hip_bfloat16* Xs = (__hip_bfloat16*)smem;             // stride 264
    __hip_bfloat16* Hs = (__hip_bfloat16*)(smem + 33792);   // stride 136
    float* gate_s = (float*)(smem + 51200);                 // [64][4]
    float* wgs = (float*)(smem + 33792);                    // aliases Hs region

    const int tid = threadIdx.x;
    const int m0 = blockIdx.x * 64;
    const bool f32m = (flag[0] != 0);

    // ---- stage X tile as bf16 ----
    if (!f32m) {
        const uint4* xg = (const uint4*)((const __hip_bfloat16*)xin + (size_t)m0 * 256);
#pragma unroll
        for (int i = 0; i < 8; ++i) {
            int f = tid + 256 * i;          // uint4 index over [64][32]
            int r = f >> 5, c = f & 31;
            *(uint4*)&Xs[r * 264 + c * 8] = xg[f];
        }
    } else {
        const float4* xg = (const float4*)((const float*)xin + (size_t)m0 * 256);
#pragma unroll
        for (int i = 0; i < 8; ++i) {
            int f = tid + 256 * i;
            int r = f >> 5, c = f & 31;
            float4 a = xg[2 * f], b = xg[2 * f + 1];
            __hip_bfloat16* d = &Xs[r * 264 + c * 8];
            d[0] = __float2bfloat16(a.x); d[1] = __float2bfloat16(a.y);
            d[2] = __float2bfloat16(a.z); d[3] = __float2bfloat16(a.w);
            d[4] = __float2bfloat16(b.x); d[5] = __float2bfloat16(b.y);
            d[6] = __float2bfloat16(b.z); d[7] = __float2bfloat16(b.w);
        }
    }
    {  // w_gate transposed to LDS as f32: wgs[e][d]  (aliases Hs -- dead after gating)
#pragma unroll
        for (int e = 0; e < 4; ++e)
            wgs[e * 256 + tid] = f32m ? ((const float*)wg)[tid * 4 + e]
                                      : bf2f(((const __hip_bfloat16*)wg)[tid * 4 + e]);
    }
    __syncthreads();

    // ---- gating logits at FULL input precision (top-k is discrete!) ----
    {
        int tok = tid >> 2, e = tid & 3;
        float acc = 0.f;
        if (f32m) {
            const float4* xrow = (const float4*)((const float*)xin + (size_t)(m0 + tok) * 256);
            const float* wrow = &wgs[e * 256];
#pragma unroll 8
            for (int q = 0; q < 64; ++q) {
                float4 xv = xrow[q];
                acc += xv.x * wrow[q * 4] + xv.y * wrow[q * 4 + 1]
                     + xv.z * wrow[q * 4 + 2] + xv.w * wrow[q * 4 + 3];
            }
        } else {
            const float* wrow = &wgs[e * 256];
#pragma unroll 4
            for (int d8 = 0; d8 < 32; ++d8) {
                bf16x8 xv = *(const bf16x8*)&Xs[tok * 264 + d8 * 8];
#pragma unroll
                for (int j = 0; j < 8; ++j) {
                    union { unsigned u; float f; } c;
                    c.u = ((unsigned)(unsigned short)xv[j]) << 16;
                    acc += c.f * wrow[d8 * 8 + j];
                }
            }
        }
        gate_s[tok * 4 + e] = acc;  // logits for now
    }
    __syncthreads();
    // top-2 + softmax (jax.lax.top_k ties -> lowest index; strict > keeps first)
    if (tid < 64) {
        float l[4];
#pragma unroll
        for (int e = 0; e < 4; ++e) l[e] = gate_s[tid * 4 + e];
        int i0 = 0; float v0 = l[0];
#pragma unroll
        for (int e = 1; e < 4; ++e)
            if (l[e] > v0) { v0 = l[e]; i0 = e; }
        int i1 = -1; float v1 = -1e30f;
#pragma unroll
        for (int e = 0; e < 4; ++e)
            if (e != i0 && l[e] > v1) { v1 = l[e]; i1 = e; }
        float t = __expf(v1 - v0);
        float g0 = 1.f / (1.f + t);
        float g1 = t * g0;
#pragma unroll
        for (int e = 0; e < 4; ++e) gate_s[tid * 4 + e] = 0.f;
        gate_s[tid * 4 + i0] = g0;
        gate_s[tid * 4 + i1] = g1;
    }
    __syncthreads();

    const int lane = tid & 63;
    const int wv = tid >> 6;       // 4 waves
    const int wr = wv & 1;         // rows 32*wr..+32
    const int wc = wv >> 1;        // col group 0/1
    const int lm = lane & 15, quad = lane >> 4;

    f32x4 Yacc[2][8];  // Y wave-tile [32][128]
#pragma unroll
    for (int a = 0; a < 2; ++a)
#pragma unroll
        for (int b = 0; b < 8; ++b) Yacc[a][b] = (f32x4){0.f, 0.f, 0.f, 0.f};

#pragma unroll 1
    for (int e = 0; e < 4; ++e) {
        const __hip_bfloat16* w1e = w1t + (e << 17);
        const __hip_bfloat16* w2e = w2t + (e << 17);
#pragma unroll 1
        for (int hc = 0; hc < 512; hc += 128) {
            // Phase A: Hc[64][128] = X @ W1e[:, hc:hc+128]; wave sub-tile [32][64]
            f32x4 Hacc[2][4];
#pragma unroll
            for (int a = 0; a < 2; ++a)
#pragma unroll
                for (int b = 0; b < 4; ++b) Hacc[a][b] = (f32x4){0.f, 0.f, 0.f, 0.f};
#pragma unroll
            for (int k = 0; k < 256; k += 32) {
                bf16x8 af[2];
#pragma unroll
                for (int mt = 0; mt < 2; ++mt)
                    af[mt] = *(const bf16x8*)&Xs[(32 * wr + 16 * mt + lm) * 264 + k + quad * 8];
#pragma unroll
                for (int nt = 0; nt < 4; ++nt) {
                    int h = hc + 64 * wc + 16 * nt + lm;
                    bf16x8 bfr = *(const bf16x8*)&w1e[(h << 8) + k + quad * 8];
                    Hacc[0][nt] = MFMA16(af[0], bfr, Hacc[0][nt]);
                    Hacc[1][nt] = MFMA16(af[1], bfr, Hacc[1][nt]);
                }
            }
            // gelu (tanh form) + gate scale -> Hs (bf16)
#pragma unroll
            for (int mt = 0; mt < 2; ++mt)
#pragma unroll
                for (int nt = 0; nt < 4; ++nt)
#pragma unroll
                    for (int r = 0; r < 4; ++r) {
                        int row = 32 * wr + 16 * mt + quad * 4 + r;
                        int col = 64 * wc + 16 * nt + lm;
                        float g = gelu_f(Hacc[mt][nt][r]);
                        g *= gate_s[row * 4 + e];
                        Hs[row * 136 + col] = __float2bfloat16(g);
                    }
            __syncthreads();
            // Phase B: Y += Hc @ W2e[hc:hc+128, :]
#pragma unroll
            for (int kk = 0; kk < 128; kk += 32) {
                bf16x8 af[2];
#pragma unroll
                for (int mt = 0; mt < 2; ++mt)
                    af[mt] = *(const bf16x8*)&Hs[(32 * wr + 16 * mt + lm) * 136 + kk + quad * 8];
#pragma unroll
                for (int nt = 0; nt < 8; ++nt) {
                    int d = 128 * wc + 16 * nt + lm;
                    bf16x8 bfr = *(const bf16x8*)&w2e[(d << 9) + hc + kk + quad * 8];
                    Yacc[0][nt] = MFMA16(af[0], bfr, Yacc[0][nt]);
                    Yacc[1][nt] = MFMA16(af[1], bfr, Yacc[1][nt]);
                }
            }
            __syncthreads();
        }
    }

    // ---- Y -> LDS (reuse Xs region; all waves past their last Xs read) ----
#pragma unroll
    for (int mt = 0; mt < 2; ++mt)
#pragma unroll
        for (int nt = 0; nt < 8; ++nt)
#pragma unroll
            for (int r = 0; r < 4; ++r) {
                int row = 32 * wr + 16 * mt + quad * 4 + r;
                int col = 128 * wc + 16 * nt + lm;
                Xs[row * 264 + col] = __float2bfloat16(Yacc[mt][nt][r]);
            }
    __syncthreads();

    // ---- projection: OUT[64][512] = Y @ Wproj + b ----
#pragma unroll 1
    for (int p = 0; p < 2; ++p) {
        int n0 = 128 * (2 * wc + p);
        f32x4 acc[2][8];
#pragma unroll
        for (int a = 0; a < 2; ++a)
#pragma unroll
            for (int b = 0; b < 8; ++b) acc[a][b] = (f32x4){0.f, 0.f, 0.f, 0.f};
#pragma unroll
        for (int k = 0; k < 256; k += 32) {
            bf16x8 af[2];
#pragma unroll
            for (int mt = 0; mt < 2; ++mt)
                af[mt] = *(const bf16x8*)&Xs[(32 * wr + 16 * mt + lm) * 264 + k + quad * 8];
#pragma unroll
            for (int nt = 0; nt < 8; ++nt) {
                int n = n0 + 16 * nt + lm;
                bf16x8 bfr = *(const bf16x8*)&wpt[(n << 8) + k + quad * 8];
                acc[0][nt] = MFMA16(af[0], bfr, acc[0][nt]);
                acc[1][nt] = MFMA16(af[1], bfr, acc[1][nt]);
            }
        }
#pragma unroll
        for (int nt = 0; nt < 8; ++nt) {
            int col = n0 + 16 * nt + lm;
            float bv = f32m ? ((const float*)bp)[col] : bf2f(((const __hip_bfloat16*)bp)[col]);
#pragma unroll
            for (int mt = 0; mt < 2; ++mt)
#pragma unroll
                for (int r = 0; r < 4; ++r) {
                    int row = m0 + 32 * wr + 16 * mt + quad * 4 + r;
                    float v = acc[mt][nt][r] + bv;
                    if (f32m) ((float*)outp)[(size_t)row * 512 + col] = v;
                    else ((__hip_bfloat16*)outp)[(size_t)row * 512 + col] = __float2bfloat16(v);
                }
        }
    }
}

extern "C" void kernel_launch(void* const* d_in, const int* in_sizes, int n_in,
                              void* d_out, int out_size, void* d_ws, size_t ws_size,
                              hipStream_t stream) {
    const void* x  = d_in[0];
    const void* wg = d_in[1];
    const void* w1 = d_in[2];
    const void* w2 = d_in[3];
    const void* wp = d_in[4];
    const void* bp = d_in[5];

    char* ws = (char*)d_ws;
    int* flag = (int*)(ws + 0);
    __hip_bfloat16* w1t = (__hip_bfloat16*)(ws + 4096);
    __hip_bfloat16* w2t = (__hip_bfloat16*)(ws + 4096 + (1u << 20));
    __hip_bfloat16* wpt = (__hip_bfloat16*)(ws + 4096 + (2u << 20));

    k_sniff<<<1, 64, 0, stream>>>((const unsigned short*)x, flag);
    k_prep<<<2048, 256, 0, stream>>>(w1, w2, wp, flag, w1t, w2t, wpt);
    k_moe<<<1024, 256, 52224, stream>>>(x, wg, w1t, w2t, wpt, bp, flag, d_out);
}

// Round 3
// 609.193 us; speedup vs baseline: 1.8738x; 1.4244x over previous
//
#include <hip/hip_runtime.h>
#include <hip/hip_bf16.h>
#include <math.h>

// MoEHeadAdapter: N=65536, D=256, E=4, H=512, K=2, EMB=512.
// Dense-expert compute (all 4 experts scaled by sparse gates) == reference einsum.
// Dtype-agnostic: k_sniff detects fp32 vs bf16 input encoding at runtime.
// ws: [0,4) flag | [4096, +1MB) W1t [4][512][256] bf16 | +1MB W2t [4][256][512] |
//     +2MB Wpt [512][256].  Total < 2.3 MB (no large intermediates).
//
// R3: weight-stream fix. R0-R2 read every MFMA B-operand straight from global
//     (reuse=2, MLP~8) -> all pipes idle, vmcnt-bound (Mfma 8%, VALU 12%, HBM 7%).
//     Now weights are staged once per block into double-buffered LDS tiles
//     (reg-staged, T14 issue-early/write-late, one barrier per 32-k step),
//     read back as ds_read_b128 from 80B-padded rows (<=2-way bank conflict).
//     X fragments hoisted to registers (ax[2][8], phase-A loop fully unrolled).

typedef __attribute__((ext_vector_type(4))) float f32x4;
typedef __attribute__((ext_vector_type(8))) short bf16x8;

#define MFMA16(a, b, c) __builtin_amdgcn_mfma_f32_16x16x32_bf16((a), (b), (c), 0, 0, 0)

__device__ __forceinline__ float bf2f(__hip_bfloat16 v) { return __bfloat162float(v); }

// tanh-form gelu: max |err| vs exact erf-gelu ~2e-4 (negligible vs bf16 rounding of H).
__device__ __forceinline__ float gelu_f(float v) {
    float t = 0.7978845608028654f * v * (1.f + 0.044715f * v * v);
    float e = __expf(2.f * t);                       // e^{2t}; inf/0 limits give +/-1 tanh
    float th = 1.f - 2.f * __builtin_amdgcn_rcpf(e + 1.f);
    return 0.5f * v * (1.f + th);
}

// ---- weight tile staging: global -> regs (issue early) -> LDS (write late) ----
// Tile = nrows x 32 bf16 (64 B/row from global, 80 B/row padded in LDS).
// nrows=128: 1 uint4/thread; nrows=256: 2 uint4/thread. Called with literal nrows.
__device__ __forceinline__ void stg_ld(const char* base, int rs, int nrows,
                                       uint4* s, int tid) {
    s[0] = *(const uint4*)(base + (tid >> 2) * rs + (tid & 3) * 16);
    if (nrows == 256) {
        int i2 = tid + 512;
        s[1] = *(const uint4*)(base + (i2 >> 2) * rs + (i2 & 3) * 16);
    }
}
__device__ __forceinline__ void stg_wr(char* wb, int nrows, const uint4* s, int tid) {
    *(uint4*)(wb + (tid >> 2) * 80 + (tid & 3) * 16) = s[0];
    if (nrows == 256) {
        int i2 = tid + 512;
        *(uint4*)(wb + (i2 >> 2) * 80 + (i2 & 3) * 16) = s[1];
    }
}

// ---------------- K-1: dtype sniff ----------------
__global__ void k_sniff(const unsigned short* __restrict__ xr, int* __restrict__ flag) {
    int lane = threadIdx.x;
    int cnt = 0;
#pragma unroll
    for (int j = 0; j < 4; ++j) {
        unsigned short v = xr[2 * (lane * 4 + j)];
        int e = (v >> 7) & 0xFF;
        cnt += (e >= 97 && e <= 157) ? 1 : 0;
    }
#pragma unroll
    for (int off = 32; off; off >>= 1) cnt += __shfl_down(cnt, off);
    if (lane == 0) flag[0] = (cnt < 192) ? 1 : 0;  // 1 = fp32 mode
}

// ---------------- K0: weight transposes -> bf16 ----------------
__global__ void k_prep(const void* __restrict__ w1,   // [4][256][512]
                       const void* __restrict__ w2,   // [4][512][256]
                       const void* __restrict__ wp,   // [256][512]
                       const int* __restrict__ flag,
                       __hip_bfloat16* __restrict__ w1t,   // [4][512][256]
                       __hip_bfloat16* __restrict__ w2t,   // [4][256][512]
                       __hip_bfloat16* __restrict__ wpt) { // [512][256]
    int i = blockIdx.x * 256 + threadIdx.x;  // [0, 524288)
    const bool f32m = (flag[0] != 0);
    {   // w1t[e][h][d] = w1[e][d][h]
        int e = i >> 17, j = i & 131071;
        int h = j >> 8, d = j & 255;
        int s = (e << 17) + (d << 9) + h;
        w1t[i] = f32m ? __float2bfloat16(((const float*)w1)[s]) : ((const __hip_bfloat16*)w1)[s];
    }
    {   // w2t[e][d][h] = w2[e][h][d]
        int e = i >> 17, j = i & 131071;
        int d = j >> 9, h = j & 511;
        int s = (e << 17) + (h << 8) + d;
        w2t[i] = f32m ? __float2bfloat16(((const float*)w2)[s]) : ((const __hip_bfloat16*)w2)[s];
    }
    if (i < 131072) {  // wpt[n][d] = wp[d][n]
        int n = i >> 8, d = i & 255;
        int s = (d << 9) + n;
        wpt[i] = f32m ? __float2bfloat16(((const float*)wp)[s]) : ((const __hip_bfloat16*)wp)[s];
    }
}

// ---------------- fused: gating + dense expert FFN + out projection ----------------
// grid 512 x 512 threads; block = 128 tokens; 8 waves (wr=wv&3 row strip, wc=wv>>2).
// LDS layout (145408 B total -> 1 block/CU):
//   Xs [128][264] bf16 @0       (67584)   (later reused to stash Y)
//   Hs [128][136] bf16 @67584   (34816)   (wgs [4][256] f32 aliases, dead after gating)
//   gate_s [128][4] f32 @102400 (2048)
//   wb0 @104448 (20480) | wb1 @124928 (20480)   double-buffered weight tiles
__global__ __launch_bounds__(512, 2) void k_moe(
    const void* __restrict__ xin,     // [65536][256]
    const void* __restrict__ wg,      // [256][4]
    const __hip_bfloat16* __restrict__ w1t,   // [4][512][256]
    const __hip_bfloat16* __restrict__ w2t,   // [4][256][512]
    const __hip_bfloat16* __restrict__ wpt,   // [512][256]
    const void* __restrict__ bp,      // [512]
    const int* __restrict__ flag,
    void* __restrict__ outp) {        // [65536][512]
    extern __shared__ char smem[];
    __hip_bfloat16* Xs = (__hip_bfloat16*)smem;             // stride 264 (528B = 33*16)
    __hip_bfloat16* Hs = (__hip_bfloat16*)(smem + 67584);   // stride 136 (272B = 17*16)
    float* gate_s = (float*)(smem + 102400);                // [128][4]
    float* wgs = (float*)(smem + 67584);                    // aliases Hs region
    char* wb0 = smem + 104448;
    char* wb1 = smem + 124928;

    const int tid = threadIdx.x;
    const int m0 = blockIdx.x * 128;
    const bool f32m = (flag[0] != 0);

    // ---- stage X tile as bf16 ----
    if (!f32m) {
        const uint4* xg = (const uint4*)((const __hip_bfloat16*)xin + (size_t)m0 * 256);
#pragma unroll
        for (int i = 0; i < 8; ++i) {
            int f = tid + 512 * i;          // uint4 index over [128][32]
            int r = f >> 5, c = f & 31;
            *(uint4*)&Xs[r * 264 + c * 8] = xg[f];
        }
    } else {
        const float4* xg = (const float4*)((const float*)xin + (size_t)m0 * 256);
#pragma unroll
        for (int i = 0; i < 8; ++i) {
            int f = tid + 512 * i;
            int r = f >> 5, c = f & 31;
            float4 a = xg[2 * f], b = xg[2 * f + 1];
            __hip_bfloat16* d = &Xs[r * 264 + c * 8];
            d[0] = __float2bfloat16(a.x); d[1] = __float2bfloat16(a.y);
            d[2] = __float2bfloat16(a.z); d[3] = __float2bfloat16(a.w);
            d[4] = __float2bfloat16(b.x); d[5] = __float2bfloat16(b.y);
            d[6] = __float2bfloat16(b.z); d[7] = __float2bfloat16(b.w);
        }
    }
    if (tid < 256) {  // w_gate transposed to LDS as f32: wgs[e][d] (aliases Hs)
#pragma unroll
        for (int e = 0; e < 4; ++e)
            wgs[e * 256 + tid] = f32m ? ((const float*)wg)[tid * 4 + e]
                                      : bf2f(((const __hip_bfloat16*)wg)[tid * 4 + e]);
    }
    __syncthreads();

    // ---- gating logits at FULL input precision (top-k is discrete!) ----
    {
        int tok = tid >> 2, ge = tid & 3;
        float acc = 0.f;
        if (f32m) {
            const float4* xrow = (const float4*)((const float*)xin + (size_t)(m0 + tok) * 256);
            const float* wrow = &wgs[ge * 256];
#pragma unroll 8
            for (int q = 0; q < 64; ++q) {
                float4 xv = xrow[q];
                acc += xv.x * wrow[q * 4] + xv.y * wrow[q * 4 + 1]
                     + xv.z * wrow[q * 4 + 2] + xv.w * wrow[q * 4 + 3];
            }
        } else {
            const float* wrow = &wgs[ge * 256];
#pragma unroll 4
            for (int d8 = 0; d8 < 32; ++d8) {
                bf16x8 xv = *(const bf16x8*)&Xs[tok * 264 + d8 * 8];
#pragma unroll
                for (int j = 0; j < 8; ++j) {
                    union { unsigned u; float f; } c;
                    c.u = ((unsigned)(unsigned short)xv[j]) << 16;
                    acc += c.f * wrow[d8 * 8 + j];
                }
            }
        }
        gate_s[tok * 4 + ge] = acc;  // logits for now
    }
    __syncthreads();
    // top-2 + softmax (jax.lax.top_k ties -> lowest index; strict > keeps first)
    if (tid < 128) {
        float l[4];
#pragma unroll
        for (int e = 0; e < 4; ++e) l[e] = gate_s[tid * 4 + e];
        int i0 = 0; float v0 = l[0];
#pragma unroll
        for (int e = 1; e < 4; ++e)
            if (l[e] > v0) { v0 = l[e]; i0 = e; }
        int i1 = -1; float v1 = -1e30f;
#pragma unroll
        for (int e = 0; e < 4; ++e)
            if (e != i0 && l[e] > v1) { v1 = l[e]; i1 = e; }
        float t = __expf(v1 - v0);
        float g0 = 1.f / (1.f + t);
        float g1 = t * g0;
#pragma unroll
        for (int e = 0; e < 4; ++e) gate_s[tid * 4 + e] = 0.f;
        gate_s[tid * 4 + i0] = g0;
        gate_s[tid * 4 + i1] = g1;
    }
    __syncthreads();

    const int lane = tid & 63;
    const int wv = tid >> 6;       // 8 waves
    const int wr = wv & 3;         // rows 32*wr..+32
    const int wc = wv >> 2;        // col group 0/1
    const int lm = lane & 15, quad = lane >> 4;
    const char* w1c = (const char*)w1t;
    const char* w2c = (const char*)w2t;
    const char* wpc = (const char*)wpt;

    // ---- prologue: stage W1(e=0,hc=0,k=0) while hoisting X frags to regs ----
    uint4 sreg[2];
    stg_ld(w1c, 512, 128, sreg, tid);            // loads in flight...
    bf16x8 ax[2][8];                             // ...overlap with LDS reads
#pragma unroll
    for (int mt = 0; mt < 2; ++mt)
#pragma unroll
        for (int ks = 0; ks < 8; ++ks)
            ax[mt][ks] = *(const bf16x8*)&Xs[(32 * wr + 16 * mt + lm) * 264 + ks * 32 + quad * 8];
    stg_wr(wb0, 128, sreg, tid);
    __syncthreads();
    char* wcur = wb0;
    char* wnxt = wb1;

    f32x4 Yacc[2][8];  // Y wave-tile [32][128]
#pragma unroll
    for (int a = 0; a < 2; ++a)
#pragma unroll
        for (int b = 0; b < 8; ++b) Yacc[a][b] = (f32x4){0.f, 0.f, 0.f, 0.f};

#pragma unroll 1
    for (int e = 0; e < 4; ++e) {
#pragma unroll 1
        for (int hc = 0; hc < 512; hc += 128) {
            // ---- Phase A: Hc[128][128] = X @ W1e[:, hc:+128], k-steps of 32 ----
            f32x4 Hacc[2][4];
#pragma unroll
            for (int a = 0; a < 2; ++a)
#pragma unroll
                for (int b = 0; b < 4; ++b) Hacc[a][b] = (f32x4){0.f, 0.f, 0.f, 0.f};
#pragma unroll
            for (int t = 0; t < 8; ++t) {        // fully unrolled: ax[.][t] static
                if (t < 7)
                    stg_ld(w1c + (((e << 17) + (hc << 8) + 32 * (t + 1)) << 1), 512, 128, sreg, tid);
                else
                    stg_ld(w2c + (((e << 17) + hc) << 1), 1024, 256, sreg, tid);
#pragma unroll
                for (int nt = 0; nt < 4; ++nt) {
                    bf16x8 b = *(const bf16x8*)(wcur + (64 * wc + 16 * nt + lm) * 80 + quad * 16);
                    Hacc[0][nt] = MFMA16(ax[0][t], b, Hacc[0][nt]);
                    Hacc[1][nt] = MFMA16(ax[1][t], b, Hacc[1][nt]);
                }
                if (t == 7) {
                    // gelu + gate scale -> Hs (bf16); hides the W2 load latency
#pragma unroll
                    for (int mt = 0; mt < 2; ++mt)
#pragma unroll
                        for (int nt = 0; nt < 4; ++nt)
#pragma unroll
                            for (int r = 0; r < 4; ++r) {
                                int row = 32 * wr + 16 * mt + quad * 4 + r;
                                int col = 64 * wc + 16 * nt + lm;
                                float g = gelu_f(Hacc[mt][nt][r]) * gate_s[row * 4 + e];
                                Hs[row * 136 + col] = __float2bfloat16(g);
                            }
                    stg_wr(wnxt, 256, sreg, tid);
                } else {
                    stg_wr(wnxt, 128, sreg, tid);
                }
                __syncthreads();
                { char* tp = wcur; wcur = wnxt; wnxt = tp; }
            }
            // ---- Phase B: Y += Hc @ W2e[hc:+128, :], kk-steps of 32 ----
#pragma unroll 1
            for (int t = 0; t < 4; ++t) {
                bool adv = (t == 3);
                bool last_eh = (e == 3 && hc == 384);
                if (!adv) {
                    stg_ld(w2c + (((e << 17) + hc + 32 * (t + 1)) << 1), 1024, 256, sreg, tid);
                } else if (!last_eh) {
                    int e2 = (hc < 384) ? e : e + 1;
                    int h2 = (hc < 384) ? hc + 128 : 0;
                    stg_ld(w1c + (((e2 << 17) + (h2 << 8)) << 1), 512, 128, sreg, tid);
                } else {
                    stg_ld(wpc, 512, 256, sreg, tid);   // proj p=0, k=0
                }
                bf16x8 af0 = *(const bf16x8*)&Hs[(32 * wr + lm) * 136 + 32 * t + quad * 8];
                bf16x8 af1 = *(const bf16x8*)&Hs[(32 * wr + 16 + lm) * 136 + 32 * t + quad * 8];
#pragma unroll
                for (int nt = 0; nt < 8; ++nt) {
                    bf16x8 b = *(const bf16x8*)(wcur + (128 * wc + 16 * nt + lm) * 80 + quad * 16);
                    Yacc[0][nt] = MFMA16(af0, b, Yacc[0][nt]);
                    Yacc[1][nt] = MFMA16(af1, b, Yacc[1][nt]);
                }
                if (!adv) stg_wr(wnxt, 256, sreg, tid);
                else if (!last_eh) stg_wr(wnxt, 128, sreg, tid);
                else stg_wr(wnxt, 256, sreg, tid);
                __syncthreads();
                { char* tp = wcur; wcur = wnxt; wnxt = tp; }
            }
        }
    }

    // ---- Y -> LDS (reuse Xs region; all Xs consumers done) ----
#pragma unroll
    for (int mt = 0; mt < 2; ++mt)
#pragma unroll
        for (int nt = 0; nt < 8; ++nt)
#pragma unroll
            for (int r = 0; r < 4; ++r) {
                int row = 32 * wr + 16 * mt + quad * 4 + r;
                int col = 128 * wc + 16 * nt + lm;
                Xs[row * 264 + col] = __float2bfloat16(Yacc[mt][nt][r]);
            }
    __syncthreads();

    // ---- projection: OUT[128][512] = Y @ Wproj + b; Wp tiles staged like W2 ----
#pragma unroll 1
    for (int p = 0; p < 2; ++p) {
        f32x4 acc[2][8];
#pragma unroll
        for (int a = 0; a < 2; ++a)
#pragma unroll
            for (int b = 0; b < 8; ++b) acc[a][b] = (f32x4){0.f, 0.f, 0.f, 0.f};
#pragma unroll 1
        for (int t = 0; t < 8; ++t) {
            bool hn = !(p == 1 && t == 7);
            if (hn) {
                int pn = (t < 7) ? p : 1;
                int kn = (t < 7) ? 32 * (t + 1) : 0;
                stg_ld(wpc + (((pn << 16) + kn) << 1), 512, 256, sreg, tid);
            }
            bf16x8 af0 = *(const bf16x8*)&Xs[(32 * wr + lm) * 264 + 32 * t + quad * 8];
            bf16x8 af1 = *(const bf16x8*)&Xs[(32 * wr + 16 + lm) * 264 + 32 * t + quad * 8];
#pragma unroll
            for (int nt = 0; nt < 8; ++nt) {
                bf16x8 b = *(const bf16x8*)(wcur + (128 * wc + 16 * nt + lm) * 80 + quad * 16);
                acc[0][nt] = MFMA16(af0, b, acc[0][nt]);
                acc[1][nt] = MFMA16(af1, b, acc[1][nt]);
            }
            if (hn) stg_wr(wnxt, 256, sreg, tid);
            __syncthreads();
            { char* tp = wcur; wcur = wnxt; wnxt = tp; }
        }
#pragma unroll
        for (int nt = 0; nt < 8; ++nt) {
            int col = 256 * p + 128 * wc + 16 * nt + lm;
            float bv = f32m ? ((const float*)bp)[col] : bf2f(((const __hip_bfloat16*)bp)[col]);
#pragma unroll
            for (int mt = 0; mt < 2; ++mt)
#pragma unroll
                for (int r = 0; r < 4; ++r) {
                    int row = m0 + 32 * wr + 16 * mt + quad * 4 + r;
                    float v = acc[mt][nt][r] + bv;
                    if (f32m) ((float*)outp)[(size_t)row * 512 + col] = v;
                    else ((__hip_bfloat16*)outp)[(size_t)row * 512 + col] = __float2bfloat16(v);
                }
        }
    }
}

extern "C" void kernel_launch(void* const* d_in, const int* in_sizes, int n_in,
                              void* d_out, int out_size, void* d_ws, size_t ws_size,
                              hipStream_t stream) {
    const void* x  = d_in[0];
    const void* wg = d_in[1];
    const void* w1 = d_in[2];
    const void* w2 = d_in[3];
    const void* wp = d_in[4];
    const void* bp = d_in[5];

    char* ws = (char*)d_ws;
    int* flag = (int*)(ws + 0);
    __hip_bfloat16* w1t = (__hip_bfloat16*)(ws + 4096);
    __hip_bfloat16* w2t = (__hip_bfloat16*)(ws + 4096 + (1u << 20));
    __hip_bfloat16* wpt = (__hip_bfloat16*)(ws + 4096 + (2u << 20));

    k_sniff<<<1, 64, 0, stream>>>((const unsigned short*)x, flag);
    k_prep<<<2048, 256, 0, stream>>>(w1, w2, wp, flag, w1t, w2t, wpt);
    k_moe<<<512, 512, 145408, stream>>>(x, wg, w1t, w2t, wpt, bp, flag, d_out);
}

// Round 4
// 409.378 us; speedup vs baseline: 2.7883x; 1.4881x over previous
//
#include <hip/hip_runtime.h>
#include <hip/hip_bf16.h>
#include <math.h>

// MoEHeadAdapter: N=65536, D=256, E=4, H=512, K=2, EMB=512.
// Dense-expert compute (all 4 experts scaled by sparse gates) == reference einsum.
// Dtype-agnostic: k_sniff detects fp32 vs bf16 input encoding at runtime.
//
// R4: stage-ordered weight STREAM + global_load_lds + counted vmcnt (T3/T4).
//   k_prep writes ws stream: 144 x 16KB tiles in exact consumption order,
//   pre-swizzled so linear gload_lds dest + XOR'd ds_read_b128 is conflict-free.
//   Stream order: for e(4) for hc(4): A0..A3 (W1 [128h][128B k-chunk]),
//                 B0..B3 (W2 [256d][64B h-chunk]); then P0..P15 (Wp [256n][64B]).
//   k_moe main loop: per 16KB stage {issue gload_lds s+2; vmcnt(4); s_barrier;
//   16 MFMA/wave}. 4-slot ring (64KB) overlays dead Xs region; proj uses a
//   2-slot ring in dead Hs region. Raw s_barrier (no vmcnt(0) drain in loop).
// ws: [0,4) flag | [4096, +2.25MB) stream.

typedef __attribute__((ext_vector_type(4))) float f32x4;
typedef __attribute__((ext_vector_type(8))) short bf16x8;
typedef unsigned int u32;

#define MFMA16(a, b, c) __builtin_amdgcn_mfma_f32_16x16x32_bf16((a), (b), (c), 0, 0, 0)

#define WAITVM4() asm volatile("s_waitcnt vmcnt(4)" ::: "memory")
#define WAITVM2() asm volatile("s_waitcnt vmcnt(2)" ::: "memory")
#define WAITVM0() asm volatile("s_waitcnt vmcnt(0)" ::: "memory")
#define WAITLG0() asm volatile("s_waitcnt lgkmcnt(0)" ::: "memory")
#define SBAR() do { __builtin_amdgcn_sched_barrier(0); \
                    __builtin_amdgcn_s_barrier(); \
                    __builtin_amdgcn_sched_barrier(0); } while (0)
#define GLDS16(g, l) __builtin_amdgcn_global_load_lds( \
    (const __attribute__((address_space(1))) u32*)(g), \
    (__attribute__((address_space(3))) u32*)(l), 16, 0, 0)

__device__ __forceinline__ float bf2f(__hip_bfloat16 v) { return __bfloat162float(v); }

// tanh-form gelu: max |err| vs exact erf-gelu ~2e-4 (negligible vs bf16 rounding of H).
__device__ __forceinline__ float gelu_f(float v) {
    float t = 0.7978845608028654f * v * (1.f + 0.044715f * v * v);
    float e = __expf(2.f * t);
    float th = 1.f - 2.f * __builtin_amdgcn_rcpf(e + 1.f);
    return 0.5f * v * (1.f + th);
}

// ---------------- K-1: dtype sniff ----------------
__global__ void k_sniff(const unsigned short* __restrict__ xr, int* __restrict__ flag) {
    int lane = threadIdx.x;
    int cnt = 0;
#pragma unroll
    for (int j = 0; j < 4; ++j) {
        unsigned short v = xr[2 * (lane * 4 + j)];
        int e = (v >> 7) & 0xFF;
        cnt += (e >= 97 && e <= 157) ? 1 : 0;
    }
#pragma unroll
    for (int off = 32; off; off >>= 1) cnt += __shfl_down(cnt, off);
    if (lane == 0) flag[0] = (cnt < 192) ? 1 : 0;  // 1 = fp32 mode
}

// ---------------- K0: build the stage-ordered, pre-swizzled weight stream ----------------
// 147456 granules of 16B. Thread = one granule; row-fast mapping so the 8 strided
// source reads are coalesced across the wave; 16B vector write.
__global__ void k_prep(const void* __restrict__ w1,   // [4][256][512]
                       const void* __restrict__ w2,   // [4][512][256]
                       const void* __restrict__ wp,   // [256][512]
                       const int* __restrict__ flag,
                       char* __restrict__ stream) {
    int G = blockIdx.x * 256 + threadIdx.x;   // [0, 147456)
    int s = G >> 10, q = G & 1023;
    const bool f32m = (flag[0] != 0);
    const void* W;
    int srcBase, stride, dpos;
    if (s < 128) {
        int e = s >> 5, r = s & 31, hci = r >> 3, stl = r & 7;
        if (stl < 4) {      // A-tile: [128 rows=h][8 granules], granule g covers k=64*stl+8g..+7
            int row = q & 127, gpos = q >> 7;
            int g = gpos ^ (row & 7);                 // inverse of read-side XOR
            int h = hci * 128 + row;
            int kb = stl * 64 + g * 8;
            W = w1; srcBase = (e << 17) + (kb << 9) + h; stride = 512;  // w1[e][kb+j][h]
            dpos = (s << 14) + row * 128 + gpos * 16;
        } else {            // B-tile: [256 rows=d][4 granules], granule g covers h=hc+32*(stl-4)+8g..+7
            int row = q & 255, gpos = q >> 8;
            int g = gpos ^ ((row >> 1) & 3);
            int hb = hci * 128 + (stl - 4) * 32 + g * 8;
            W = w2; srcBase = (e << 17) + (hb << 8) + row; stride = 256; // w2[e][hb+j][row]
            dpos = (s << 14) + row * 64 + gpos * 16;
        }
    } else {                // P-tile: [256 rows=n][4 granules], granule g covers k=32*t+8g..+7
        int ps = s - 128;
        int row = q & 255, gpos = q >> 8;
        int g = gpos ^ ((row >> 1) & 3);
        int n = (ps >> 3) * 256 + row;
        int kb = (ps & 7) * 32 + g * 8;
        W = wp; srcBase = (kb << 9) + n; stride = 512;                   // wp[kb+j][n]
        dpos = (s << 14) + row * 64 + gpos * 16;
    }
    union { unsigned short u[8]; uint4 v; } o;
#pragma unroll
    for (int j = 0; j < 8; ++j) {
        int si = srcBase + j * stride;
        if (f32m) {
            union { __hip_bfloat16 b; unsigned short u; } c;
            c.b = __float2bfloat16(((const float*)W)[si]);
            o.u[j] = c.u;
        } else {
            o.u[j] = ((const unsigned short*)W)[si];
        }
    }
    *(uint4*)(stream + dpos) = o.v;
}

// ---------------- fused: gating + dense expert FFN + out projection ----------------
// grid 512 x 512 threads; block = 128 tokens; 8 waves (wr=wv&3 rows, wc=wv>>2 cols).
// LDS (104448 B):
//   [0, 67584)       Xs [128][264] bf16 during prologue; then 4x16KB ring; then Ys [128][260]
//   [67584, 102400)  Hs [128][136] bf16 (wgs aliases during gating); proj 2x16KB ring at end
//   [102400, 104448) gate_s [128][4] f32
__global__ __launch_bounds__(512, 2) void k_moe(
    const void* __restrict__ xin,     // [65536][256]
    const void* __restrict__ wg,      // [256][4]
    const char* __restrict__ stream,  // 144 x 16KB
    const void* __restrict__ bp,      // [512]
    const int* __restrict__ flag,
    void* __restrict__ outp) {        // [65536][512]
    extern __shared__ char smem[];
    __hip_bfloat16* Xs = (__hip_bfloat16*)smem;             // stride 264
    __hip_bfloat16* Hs = (__hip_bfloat16*)(smem + 67584);   // stride 136
    float* gate_s = (float*)(smem + 102400);
    float* wgs = (float*)(smem + 67584);                    // aliases Hs (dead after gating)
    __hip_bfloat16* Ys = (__hip_bfloat16*)smem;             // stride 260 (post-expert)
    char* ring = smem;                                      // 4 x 16384 (post-gating)
    char* pring = smem + 67584;                             // 2 x 16384 (proj phase)

    const int tid = threadIdx.x;
    const int m0 = blockIdx.x * 128;
    const bool f32m = (flag[0] != 0);

    // ---- stage X tile as bf16 ----
    if (!f32m) {
        const uint4* xg = (const uint4*)((const __hip_bfloat16*)xin + (size_t)m0 * 256);
#pragma unroll
        for (int i = 0; i < 8; ++i) {
            int f = tid + 512 * i;
            int r = f >> 5, c = f & 31;
            *(uint4*)&Xs[r * 264 + c * 8] = xg[f];
        }
    } else {
        const float4* xg = (const float4*)((const float*)xin + (size_t)m0 * 256);
#pragma unroll
        for (int i = 0; i < 8; ++i) {
            int f = tid + 512 * i;
            int r = f >> 5, c = f & 31;
            float4 a = xg[2 * f], b = xg[2 * f + 1];
            __hip_bfloat16* d = &Xs[r * 264 + c * 8];
            d[0] = __float2bfloat16(a.x); d[1] = __float2bfloat16(a.y);
            d[2] = __float2bfloat16(a.z); d[3] = __float2bfloat16(a.w);
            d[4] = __float2bfloat16(b.x); d[5] = __float2bfloat16(b.y);
            d[6] = __float2bfloat16(b.z); d[7] = __float2bfloat16(b.w);
        }
    }
    if (tid < 256) {  // w_gate transposed to LDS as f32: wgs[e][d]
#pragma unroll
        for (int e = 0; e < 4; ++e)
            wgs[e * 256 + tid] = f32m ? ((const float*)wg)[tid * 4 + e]
                                      : bf2f(((const __hip_bfloat16*)wg)[tid * 4 + e]);
    }
    __syncthreads();

    // ---- gating logits at FULL input precision (top-k is discrete!) ----
    {
        int tok = tid >> 2, ge = tid & 3;
        float acc = 0.f;
        if (f32m) {
            const float4* xrow = (const float4*)((const float*)xin + (size_t)(m0 + tok) * 256);
            const float* wrow = &wgs[ge * 256];
#pragma unroll 8
            for (int qd = 0; qd < 64; ++qd) {
                float4 xv = xrow[qd];
                acc += xv.x * wrow[qd * 4] + xv.y * wrow[qd * 4 + 1]
                     + xv.z * wrow[qd * 4 + 2] + xv.w * wrow[qd * 4 + 3];
            }
        } else {
            const float* wrow = &wgs[ge * 256];
#pragma unroll 4
            for (int d8 = 0; d8 < 32; ++d8) {
                bf16x8 xv = *(const bf16x8*)&Xs[tok * 264 + d8 * 8];
#pragma unroll
                for (int j = 0; j < 8; ++j) {
                    union { unsigned u; float f; } c;
                    c.u = ((unsigned)(unsigned short)xv[j]) << 16;
                    acc += c.f * wrow[d8 * 8 + j];
                }
            }
        }
        gate_s[tok * 4 + ge] = acc;
    }
    __syncthreads();
    if (tid < 128) {   // top-2 + softmax
        float l[4];
#pragma unroll
        for (int e = 0; e < 4; ++e) l[e] = gate_s[tid * 4 + e];
        int i0 = 0; float v0 = l[0];
#pragma unroll
        for (int e = 1; e < 4; ++e)
            if (l[e] > v0) { v0 = l[e]; i0 = e; }
        int i1 = -1; float v1 = -1e30f;
#pragma unroll
        for (int e = 0; e < 4; ++e)
            if (e != i0 && l[e] > v1) { v1 = l[e]; i1 = e; }
        float t = __expf(v1 - v0);
        float g0 = 1.f / (1.f + t);
        float g1 = t * g0;
#pragma unroll
        for (int e = 0; e < 4; ++e) gate_s[tid * 4 + e] = 0.f;
        gate_s[tid * 4 + i0] = g0;
        gate_s[tid * 4 + i1] = g1;
    }
    __syncthreads();

    const int lane = tid & 63;
    const int wv = tid >> 6;       // 8 waves
    const int wr = wv & 3;
    const int wc = wv >> 2;
    const int lm = lane & 15, quad = lane >> 4;
    const int swzB = quad ^ ((lm >> 1) & 3);   // B/P-tile read swizzle (const per thread)

    // ---- hoist X fragments to registers (Xs dies after this) ----
    bf16x8 ax[2][8];
#pragma unroll
    for (int mt = 0; mt < 2; ++mt)
#pragma unroll
        for (int ks = 0; ks < 8; ++ks)
            ax[mt][ks] = *(const bf16x8*)&Xs[(32 * wr + 16 * mt + lm) * 264 + ks * 32 + quad * 8];
    __syncthreads();   // all waves done reading Xs; ring may now be written

    // staging address bases (src is per-lane; lds base wave-uniform)
    const char* src_base = stream + tid * 16;
    char* dst_base = ring + ((tid >> 6) << 10);

    // prologue: stages 0,1 in flight
    {
        const char* s0 = src_base; char* d0 = dst_base;
        GLDS16(s0, d0); GLDS16(s0 + 8192, d0 + 8192);
        const char* s1 = src_base + 16384; char* d1 = dst_base + 16384;
        GLDS16(s1, d1); GLDS16(s1 + 8192, d1 + 8192);
    }

    f32x4 Yacc[2][8];
#pragma unroll
    for (int a = 0; a < 2; ++a)
#pragma unroll
        for (int b = 0; b < 8; ++b) Yacc[a][b] = (f32x4){0.f, 0.f, 0.f, 0.f};

    int sidx = 0;
#pragma unroll 1
    for (int e = 0; e < 4; ++e) {
#pragma unroll 1
        for (int hci = 0; hci < 4; ++hci) {
            f32x4 Hacc[2][4];
#pragma unroll
            for (int a = 0; a < 2; ++a)
#pragma unroll
                for (int b = 0; b < 4; ++b) Hacc[a][b] = (f32x4){0.f, 0.f, 0.f, 0.f};
#pragma unroll
            for (int stA = 0; stA < 4; ++stA) {
                int nxt = sidx + 2;
                if (nxt < 128) {
                    const char* sp = src_base + ((size_t)nxt << 14);
                    char* dp = dst_base + ((nxt & 3) << 14);
                    GLDS16(sp, dp); GLDS16(sp + 8192, dp + 8192);
                    WAITVM4();
                } else if (nxt == 128) WAITVM2(); else WAITVM0();
                SBAR();
                const char* rb = ring + ((sidx & 3) << 14);
#pragma unroll
                for (int ks = 0; ks < 2; ++ks)
#pragma unroll
                    for (int nt = 0; nt < 4; ++nt) {
                        int row = 64 * wc + 16 * nt + lm;
                        bf16x8 b = *(const bf16x8*)(rb + row * 128
                                      + ((((ks << 2) | quad) ^ (lm & 7)) << 4));
                        Hacc[0][nt] = MFMA16(ax[0][2 * stA + ks], b, Hacc[0][nt]);
                        Hacc[1][nt] = MFMA16(ax[1][2 * stA + ks], b, Hacc[1][nt]);
                    }
                ++sidx;
                if (stA == 3) {   // gelu + gate -> Hs; drain before next barrier publishes
#pragma unroll
                    for (int mt = 0; mt < 2; ++mt)
#pragma unroll
                        for (int nt = 0; nt < 4; ++nt)
#pragma unroll
                            for (int r = 0; r < 4; ++r) {
                                int row = 32 * wr + 16 * mt + quad * 4 + r;
                                int col = 64 * wc + 16 * nt + lm;
                                float g = gelu_f(Hacc[mt][nt][r]) * gate_s[row * 4 + e];
                                Hs[row * 136 + col] = __float2bfloat16(g);
                            }
                    WAITLG0();
                }
            }
#pragma unroll
            for (int stB = 0; stB < 4; ++stB) {
                int nxt = sidx + 2;
                if (nxt < 128) {
                    const char* sp = src_base + ((size_t)nxt << 14);
                    char* dp = dst_base + ((nxt & 3) << 14);
                    GLDS16(sp, dp); GLDS16(sp + 8192, dp + 8192);
                    WAITVM4();
                } else if (nxt == 128) WAITVM2(); else WAITVM0();
                SBAR();
                const char* rb = ring + ((sidx & 3) << 14);
                bf16x8 af0 = *(const bf16x8*)&Hs[(32 * wr + lm) * 136 + stB * 32 + quad * 8];
                bf16x8 af1 = *(const bf16x8*)&Hs[(32 * wr + 16 + lm) * 136 + stB * 32 + quad * 8];
#pragma unroll
                for (int nt = 0; nt < 8; ++nt) {
                    int row = 128 * wc + 16 * nt + lm;
                    bf16x8 b = *(const bf16x8*)(rb + row * 64 + (swzB << 4));
                    Yacc[0][nt] = MFMA16(af0, b, Yacc[0][nt]);
                    Yacc[1][nt] = MFMA16(af1, b, Yacc[1][nt]);
                }
                ++sidx;
            }
        }
    }

    // ---- transition to projection: issue P0/P1 into Hs-region ring, stash Y ----
    SBAR();   // all waves done with ring + Hs reads
    {
        const char* s0 = stream + ((size_t)128 << 14) + tid * 16;
        char* d0 = pring + ((tid >> 6) << 10);
        GLDS16(s0, d0); GLDS16(s0 + 8192, d0 + 8192);
        const char* s1 = s0 + 16384; char* d1 = d0 + 16384;
        GLDS16(s1, d1); GLDS16(s1 + 8192, d1 + 8192);
    }
#pragma unroll
    for (int mt = 0; mt < 2; ++mt)   // Y -> Ys (stride 260), hides P0/P1 latency
#pragma unroll
        for (int nt = 0; nt < 8; ++nt)
#pragma unroll
            for (int r = 0; r < 4; ++r) {
                int row = 32 * wr + 16 * mt + quad * 4 + r;
                int col = 128 * wc + 16 * nt + lm;
                Ys[row * 260 + col] = __float2bfloat16(Yacc[mt][nt][r]);
            }
    WAITLG0();
    WAITVM2();   // P0 landed (ours)
    SBAR();      // everyone's P0 + stash visible

    // ---- projection: OUT[128][512] = Y @ Wproj + b; 16 stages, 2-slot ring ----
    f32x4 Pacc[2][8];
#pragma unroll
    for (int a = 0; a < 2; ++a)
#pragma unroll
        for (int b = 0; b < 8; ++b) Pacc[a][b] = (f32x4){0.f, 0.f, 0.f, 0.f};
#pragma unroll 1
    for (int ps = 0; ps < 16; ++ps) {
        if (ps > 0) {
            SBAR();   // close ps-1 reads
            if (ps < 15) {
                const char* sp = stream + ((size_t)(129 + ps) << 14) + tid * 16;
                char* dp = pring + (((ps + 1) & 1) << 14) + ((tid >> 6) << 10);
                GLDS16(sp, dp); GLDS16(sp + 8192, dp + 8192);
                WAITVM2();
            } else WAITVM0();
            SBAR();
        }
        int t = ps & 7;
        const char* pb = pring + ((ps & 1) << 14);
        bf16x8 af0 = *(const bf16x8*)&Ys[(32 * wr + lm) * 260 + t * 32 + quad * 8];
        bf16x8 af1 = *(const bf16x8*)&Ys[(32 * wr + 16 + lm) * 260 + t * 32 + quad * 8];
#pragma unroll
        for (int nt = 0; nt < 8; ++nt) {
            int row = 128 * wc + 16 * nt + lm;
            bf16x8 b = *(const bf16x8*)(pb + row * 64 + (swzB << 4));
            Pacc[0][nt] = MFMA16(af0, b, Pacc[0][nt]);
            Pacc[1][nt] = MFMA16(af1, b, Pacc[1][nt]);
        }
        if (t == 7) {   // epilogue for p = ps>>3
            int p = ps >> 3;
#pragma unroll
            for (int nt = 0; nt < 8; ++nt) {
                int col = 256 * p + 128 * wc + 16 * nt + lm;
                float bv = f32m ? ((const float*)bp)[col] : bf2f(((const __hip_bfloat16*)bp)[col]);
#pragma unroll
                for (int mt = 0; mt < 2; ++mt)
#pragma unroll
                    for (int r = 0; r < 4; ++r) {
                        int row = m0 + 32 * wr + 16 * mt + quad * 4 + r;
                        float v = Pacc[mt][nt][r] + bv;
                        if (f32m) ((float*)outp)[(size_t)row * 512 + col] = v;
                        else ((__hip_bfloat16*)outp)[(size_t)row * 512 + col] = __float2bfloat16(v);
                    }
            }
            if (ps < 15) {
#pragma unroll
                for (int a = 0; a < 2; ++a)
#pragma unroll
                    for (int b = 0; b < 8; ++b) Pacc[a][b] = (f32x4){0.f, 0.f, 0.f, 0.f};
            }
        }
    }
}

extern "C" void kernel_launch(void* const* d_in, const int* in_sizes, int n_in,
                              void* d_out, int out_size, void* d_ws, size_t ws_size,
                              hipStream_t stream) {
    const void* x  = d_in[0];
    const void* wg = d_in[1];
    const void* w1 = d_in[2];
    const void* w2 = d_in[3];
    const void* wp = d_in[4];
    const void* bp = d_in[5];

    char* ws = (char*)d_ws;
    int* flag = (int*)(ws + 0);
    char* wstream = ws + 4096;   // 144 x 16384 = 2359296 B

    k_sniff<<<1, 64, 0, stream>>>((const unsigned short*)x, flag);
    k_prep<<<576, 256, 0, stream>>>(w1, w2, wp, flag, wstream);
    k_moe<<<512, 512, 104448, stream>>>(x, wg, wstream, bp, flag, d_out);
}

// Round 5
// 386.188 us; speedup vs baseline: 2.9558x; 1.0600x over previous
//
#include <hip/hip_runtime.h>
#include <hip/hip_bf16.h>
#include <math.h>

// MoEHeadAdapter: N=65536, D=256, E=4, H=512, K=2, EMB=512.
// Dense-expert compute (all 4 experts scaled by sparse gates) == reference einsum.
// Dtype-agnostic: deterministic per-thread sniff of x encoding (fp32 vs bf16).
//
// R5: 64-token blocks / 256 thr / 4 waves, LDS 66560 -> 2 independent blocks/CU
//     (R4 was 1 block/CU; ~45% idle was intra-block barrier/vmcnt/gelu bubbles).
//     3-slot ring, issue-after-barrier (slot(s+2)=slot(s-1), freed by SBAR(s)).
//     Hs/Ys: no pad, stride=0 mod 128B + XOR-swizzle byte^=(row&7)<<4 (2-way-free).
//     Gelu: 8 VALU + 2 trans, inf-safe vg*(1-rcp(e^u+1)), gate folded.
//     setprio(1) around MFMA clusters (cross-block wave diversity now exists).
// ws: [0, 2.25MB) stage-ordered pre-swizzled weight stream (144 x 16KB tiles).

typedef __attribute__((ext_vector_type(4))) float f32x4;
typedef __attribute__((ext_vector_type(8))) short bf16x8;
typedef unsigned int u32;

#define MFMA16(a, b, c) __builtin_amdgcn_mfma_f32_16x16x32_bf16((a), (b), (c), 0, 0, 0)

#define WAITVM4() asm volatile("s_waitcnt vmcnt(4)" ::: "memory")
#define WAITVM0() asm volatile("s_waitcnt vmcnt(0)" ::: "memory")
#define WAITLG0() asm volatile("s_waitcnt lgkmcnt(0)" ::: "memory")
#define SBAR() do { __builtin_amdgcn_sched_barrier(0); \
                    __builtin_amdgcn_s_barrier(); \
                    __builtin_amdgcn_sched_barrier(0); } while (0)
#define GLDS16(g, l) __builtin_amdgcn_global_load_lds( \
    (const __attribute__((address_space(1))) u32*)(g), \
    (__attribute__((address_space(3))) u32*)(l), 16, 0, 0)

__device__ __forceinline__ float bf2f(__hip_bfloat16 v) { return __bfloat162float(v); }

// Deterministic dtype sniff: every thread reads the SAME 32 even-position ushorts.
// bf16 data -> sane exponents ~100%; fp32 data -> even ushorts are mantissa bits, ~24%.
__device__ __forceinline__ bool sniff_f32(const unsigned short* __restrict__ xr) {
    int cnt = 0;
#pragma unroll
    for (int j = 0; j < 32; ++j) {
        int e = (xr[2 * j] >> 7) & 0xFF;
        cnt += (e >= 97 && e <= 157) ? 1 : 0;
    }
    return cnt < 16;
}

// ---------------- K0: build the stage-ordered, pre-swizzled weight stream ----------------
// 147456 granules of 16B; thread = one granule (row-fast -> coalesced src reads).
__global__ void k_prep(const void* __restrict__ w1,   // [4][256][512]
                       const void* __restrict__ w2,   // [4][512][256]
                       const void* __restrict__ wp,   // [256][512]
                       const unsigned short* __restrict__ xr,
                       char* __restrict__ stream) {
    int G = blockIdx.x * 256 + threadIdx.x;   // [0, 147456)
    int s = G >> 10, q = G & 1023;
    const bool f32m = sniff_f32(xr);
    const void* W;
    int srcBase, stride, dpos;
    if (s < 128) {
        int e = s >> 5, r = s & 31, hci = r >> 3, stl = r & 7;
        if (stl < 4) {      // A-tile: [128 rows=h][8 granules], granule g covers k=64*stl+8g..+7
            int row = q & 127, gpos = q >> 7;
            int g = gpos ^ (row & 7);                 // inverse of read-side XOR
            int h = hci * 128 + row;
            int kb = stl * 64 + g * 8;
            W = w1; srcBase = (e << 17) + (kb << 9) + h; stride = 512;  // w1[e][kb+j][h]
            dpos = (s << 14) + row * 128 + gpos * 16;
        } else {            // B-tile: [256 rows=d][4 granules], granule g covers h=hc+32*(stl-4)+8g..+7
            int row = q & 255, gpos = q >> 8;
            int g = gpos ^ ((row >> 1) & 3);
            int hb = hci * 128 + (stl - 4) * 32 + g * 8;
            W = w2; srcBase = (e << 17) + (hb << 8) + row; stride = 256; // w2[e][hb+j][row]
            dpos = (s << 14) + row * 64 + gpos * 16;
        }
    } else {                // P-tile: [256 rows=n][4 granules], granule g covers k=32*t+8g..+7
        int ps = s - 128;
        int row = q & 255, gpos = q >> 8;
        int g = gpos ^ ((row >> 1) & 3);
        int n = (ps >> 3) * 256 + row;
        int kb = (ps & 7) * 32 + g * 8;
        W = wp; srcBase = (kb << 9) + n; stride = 512;                   // wp[kb+j][n]
        dpos = (s << 14) + row * 64 + gpos * 16;
    }
    union { unsigned short u[8]; uint4 v; } o;
#pragma unroll
    for (int j = 0; j < 8; ++j) {
        int si = srcBase + j * stride;
        if (f32m) {
            union { __hip_bfloat16 b; unsigned short u; } c;
            c.b = __float2bfloat16(((const float*)W)[si]);
            o.u[j] = c.u;
        } else {
            o.u[j] = ((const unsigned short*)W)[si];
        }
    }
    *(uint4*)(stream + dpos) = o.v;
}

// ---------------- fused: gating + dense expert FFN + out projection ----------------
// grid 1024 x 256 threads; block = 64 tokens; 4 waves (wr=wv&1 rows, wc=wv>>1 cols).
// LDS (66560 B -> 2 blocks/CU):
//   main:     ring 3x16384 [0,49152) | Hs [64][128] swz @49152 (16384) | gate @65536 (1024)
//   prologue: Xs [64][264] [0,33792) | wgs [4][256] f32 @36864 | gate @65536
//   proj:     Ys [64][256] swz [0,32768) | Peven @32768 | Podd @49152 (Hs dead)
__global__ __launch_bounds__(256, 2) void k_moe(
    const void* __restrict__ xin,     // [65536][256]
    const void* __restrict__ wg,      // [256][4]
    const char* __restrict__ stream,  // 144 x 16KB
    const void* __restrict__ bp,      // [512]
    void* __restrict__ outp) {        // [65536][512]
    extern __shared__ char smem[];
    __hip_bfloat16* Xs = (__hip_bfloat16*)smem;             // stride 264 (prologue only)
    char* hsb = smem + 49152;                               // Hs, swizzled, stride 256B
    float* gate_s = (float*)(smem + 65536);                 // [64][4]
    float* wgs = (float*)(smem + 36864);                    // [4][256] (ring slot2, dead later)
    char* ysb = smem;                                       // Ys, swizzled, stride 512B (proj)
    char* peven = smem + 32768;                             // proj ring even
    char* podd  = smem + 49152;                             // proj ring odd (Hs dead)

    const int tid = threadIdx.x;
    const int m0 = blockIdx.x * 64;
    const bool f32m = sniff_f32((const unsigned short*)xin);

    // ---- stage X tile as bf16 ----
    if (!f32m) {
        const uint4* xg = (const uint4*)((const __hip_bfloat16*)xin + (size_t)m0 * 256);
#pragma unroll
        for (int i = 0; i < 8; ++i) {
            int f = tid + 256 * i;          // uint4 index over [64][32]
            int r = f >> 5, c = f & 31;
            *(uint4*)&Xs[r * 264 + c * 8] = xg[f];
        }
    } else {
        const float4* xg = (const float4*)((const float*)xin + (size_t)m0 * 256);
#pragma unroll
        for (int i = 0; i < 8; ++i) {
            int f = tid + 256 * i;
            int r = f >> 5, c = f & 31;
            float4 a = xg[2 * f], b = xg[2 * f + 1];
            __hip_bfloat16* d = &Xs[r * 264 + c * 8];
            d[0] = __float2bfloat16(a.x); d[1] = __float2bfloat16(a.y);
            d[2] = __float2bfloat16(a.z); d[3] = __float2bfloat16(a.w);
            d[4] = __float2bfloat16(b.x); d[5] = __float2bfloat16(b.y);
            d[6] = __float2bfloat16(b.z); d[7] = __float2bfloat16(b.w);
        }
    }
    {  // w_gate transposed to LDS as f32: wgs[e][d]
#pragma unroll
        for (int e = 0; e < 4; ++e)
            wgs[e * 256 + tid] = f32m ? ((const float*)wg)[tid * 4 + e]
                                      : bf2f(((const __hip_bfloat16*)wg)[tid * 4 + e]);
    }
    __syncthreads();

    // ---- gating logits at FULL input precision (top-k is discrete!) ----
    {
        int tok = tid >> 2, ge = tid & 3;
        float acc = 0.f;
        if (f32m) {
            const float4* xrow = (const float4*)((const float*)xin + (size_t)(m0 + tok) * 256);
            const float* wrow = &wgs[ge * 256];
#pragma unroll 8
            for (int qd = 0; qd < 64; ++qd) {
                float4 xv = xrow[qd];
                acc += xv.x * wrow[qd * 4] + xv.y * wrow[qd * 4 + 1]
                     + xv.z * wrow[qd * 4 + 2] + xv.w * wrow[qd * 4 + 3];
            }
        } else {
            const float* wrow = &wgs[ge * 256];
#pragma unroll 4
            for (int d8 = 0; d8 < 32; ++d8) {
                bf16x8 xv = *(const bf16x8*)&Xs[tok * 264 + d8 * 8];
#pragma unroll
                for (int j = 0; j < 8; ++j) {
                    union { unsigned u; float f; } c;
                    c.u = ((unsigned)(unsigned short)xv[j]) << 16;
                    acc += c.f * wrow[d8 * 8 + j];
                }
            }
        }
        gate_s[tok * 4 + ge] = acc;
    }
    __syncthreads();
    if (tid < 64) {   // top-2 + softmax (ties -> lowest index; strict > keeps first)
        float l[4];
#pragma unroll
        for (int e = 0; e < 4; ++e) l[e] = gate_s[tid * 4 + e];
        int i0 = 0; float v0 = l[0];
#pragma unroll
        for (int e = 1; e < 4; ++e)
            if (l[e] > v0) { v0 = l[e]; i0 = e; }
        int i1 = -1; float v1 = -1e30f;
#pragma unroll
        for (int e = 0; e < 4; ++e)
            if (e != i0 && l[e] > v1) { v1 = l[e]; i1 = e; }
        float t = __expf(v1 - v0);
        float g0 = 1.f / (1.f + t);
        float g1 = t * g0;
#pragma unroll
        for (int e = 0; e < 4; ++e) gate_s[tid * 4 + e] = 0.f;
        gate_s[tid * 4 + i0] = g0;
        gate_s[tid * 4 + i1] = g1;
    }
    __syncthreads();

    const int lane = tid & 63;
    const int wv = tid >> 6;       // 4 waves
    const int wr = wv & 1;         // rows 32*wr..+32
    const int wc = wv >> 1;        // col group 0/1
    const int lm = lane & 15, quad = lane >> 4;
    const int swzB = quad ^ ((lm >> 1) & 3);   // B/P-tile read swizzle

    // ---- hoist X fragments to registers (Xs dies after this) ----
    bf16x8 ax[2][8];
#pragma unroll
    for (int mt = 0; mt < 2; ++mt)
#pragma unroll
        for (int ks = 0; ks < 8; ++ks)
            ax[mt][ks] = *(const bf16x8*)&Xs[(32 * wr + 16 * mt + lm) * 264 + ks * 32 + quad * 8];
    __syncthreads();   // all waves done with Xs/wgs; ring may now be written

    const char* src_base = stream + tid * 16;
    const int woff = (tid >> 6) << 10;   // wave-uniform LDS chunk base

    // prologue: stages 0,1 in flight (slots 0,1)
    {
        const char* s0 = src_base; char* d0 = smem + woff;
        GLDS16(s0, d0); GLDS16(s0 + 4096, d0 + 4096);
        GLDS16(s0 + 8192, d0 + 8192); GLDS16(s0 + 12288, d0 + 12288);
        const char* s1 = src_base + 16384; char* d1 = smem + 16384 + woff;
        GLDS16(s1, d1); GLDS16(s1 + 4096, d1 + 4096);
        GLDS16(s1 + 8192, d1 + 8192); GLDS16(s1 + 12288, d1 + 12288);
    }

    f32x4 Yacc[2][8];
#pragma unroll
    for (int a = 0; a < 2; ++a)
#pragma unroll
        for (int b = 0; b < 8; ++b) Yacc[a][b] = (f32x4){0.f, 0.f, 0.f, 0.f};

    int sidx = 0, cur = 0;
#pragma unroll 1
    for (int e = 0; e < 4; ++e) {
#pragma unroll 1
        for (int hci = 0; hci < 4; ++hci) {
            f32x4 Hacc[2][4];
#pragma unroll
            for (int a = 0; a < 2; ++a)
#pragma unroll
                for (int b = 0; b < 4; ++b) Hacc[a][b] = (f32x4){0.f, 0.f, 0.f, 0.f};
            // ---- A-stages: H = X @ W1e[:, hc:+128], k-steps of 64 ----
#pragma unroll
            for (int stA = 0; stA < 4; ++stA) {
                WAITVM4();
                SBAR();
                {   // issue stage sidx+2 into slot (cur+2)%3
                    int ns = cur + 2; if (ns >= 3) ns -= 3;
                    const char* sp = src_base + ((size_t)(sidx + 2) << 14);
                    char* dp = smem + ns * 16384 + woff;
                    GLDS16(sp, dp); GLDS16(sp + 4096, dp + 4096);
                    GLDS16(sp + 8192, dp + 8192); GLDS16(sp + 12288, dp + 12288);
                }
                const char* rb = smem + cur * 16384;
                __builtin_amdgcn_s_setprio(1);
#pragma unroll
                for (int ks = 0; ks < 2; ++ks)
#pragma unroll
                    for (int nt = 0; nt < 4; ++nt) {
                        int rown = 64 * wc + 16 * nt + lm;
                        bf16x8 b = *(const bf16x8*)(rb + rown * 128
                                      + ((((ks << 2) | quad) ^ (lm & 7)) << 4));
                        Hacc[0][nt] = MFMA16(ax[0][2 * stA + ks], b, Hacc[0][nt]);
                        Hacc[1][nt] = MFMA16(ax[1][2 * stA + ks], b, Hacc[1][nt]);
                    }
                __builtin_amdgcn_s_setprio(0);
                if (stA == 3) {   // gelu + gate -> Hs (swizzled); drain ds_writes
#pragma unroll
                    for (int mt = 0; mt < 2; ++mt)
#pragma unroll
                        for (int nt = 0; nt < 4; ++nt)
#pragma unroll
                            for (int r = 0; r < 4; ++r) {
                                int row = 32 * wr + 16 * mt + quad * 4 + r;
                                int col = 64 * wc + 16 * nt + lm;
                                float v = Hacc[mt][nt][r];
                                float vv = v * v;
                                float w = fmaf(0.044715f, vv, 1.0f);
                                float u = 1.5957691216f * v * w;
                                float ex = __expf(u);
                                float rr = __builtin_amdgcn_rcpf(ex + 1.0f);
                                float vg = v * gate_s[row * 4 + e];
                                float res = fmaf(-vg, rr, vg);   // vg*(1-r); inf-safe
                                *(__hip_bfloat16*)(hsb + row * 256
                                    + ((col * 2) ^ ((row & 7) << 4))) = __float2bfloat16(res);
                            }
                    WAITLG0();
                }
                ++sidx; cur = (cur < 2) ? cur + 1 : 0;
            }
            // ---- B-stages: Y += H @ W2e[hc:+128, :], k-steps of 32 ----
#pragma unroll
            for (int stB = 0; stB < 4; ++stB) {
                if (sidx == 127) WAITVM0(); else WAITVM4();
                SBAR();
                if (sidx + 2 <= 127) {
                    int ns = cur + 2; if (ns >= 3) ns -= 3;
                    const char* sp = src_base + ((size_t)(sidx + 2) << 14);
                    char* dp = smem + ns * 16384 + woff;
                    GLDS16(sp, dp); GLDS16(sp + 4096, dp + 4096);
                    GLDS16(sp + 8192, dp + 8192); GLDS16(sp + 12288, dp + 12288);
                }
                const char* rb = smem + cur * 16384;
                int r0 = 32 * wr + lm;
                bf16x8 af0 = *(const bf16x8*)(hsb + r0 * 256
                                + ((stB * 64 + quad * 16) ^ ((r0 & 7) << 4)));
                bf16x8 af1 = *(const bf16x8*)(hsb + (r0 + 16) * 256
                                + ((stB * 64 + quad * 16) ^ ((r0 & 7) << 4)));
                __builtin_amdgcn_s_setprio(1);
#pragma unroll
                for (int nt = 0; nt < 8; ++nt) {
                    int rown = 128 * wc + 16 * nt + lm;
                    bf16x8 b = *(const bf16x8*)(rb + rown * 64 + (swzB << 4));
                    Yacc[0][nt] = MFMA16(af0, b, Yacc[0][nt]);
                    Yacc[1][nt] = MFMA16(af1, b, Yacc[1][nt]);
                }
                __builtin_amdgcn_s_setprio(0);
                ++sidx; cur = (cur < 2) ? cur + 1 : 0;
            }
        }
    }

    // ---- transition: issue P0/P1, stash Y (swizzled) into dead ring slots ----
    SBAR();   // all waves done with ring + Hs
    {
        const char* s0 = stream + ((size_t)128 << 14) + tid * 16;
        char* d0 = peven + woff;
        GLDS16(s0, d0); GLDS16(s0 + 4096, d0 + 4096);
        GLDS16(s0 + 8192, d0 + 8192); GLDS16(s0 + 12288, d0 + 12288);
        const char* s1 = stream + ((size_t)129 << 14) + tid * 16;
        char* d1 = podd + woff;
        GLDS16(s1, d1); GLDS16(s1 + 4096, d1 + 4096);
        GLDS16(s1 + 8192, d1 + 8192); GLDS16(s1 + 12288, d1 + 12288);
    }
#pragma unroll
    for (int mt = 0; mt < 2; ++mt)   // Y -> Ys (hides P0/P1 latency)
#pragma unroll
        for (int nt = 0; nt < 8; ++nt)
#pragma unroll
            for (int r = 0; r < 4; ++r) {
                int row = 32 * wr + 16 * mt + quad * 4 + r;
                int col = 128 * wc + 16 * nt + lm;
                *(__hip_bfloat16*)(ysb + row * 512
                    + ((col * 2) ^ ((row & 7) << 4))) = __float2bfloat16(Yacc[mt][nt][r]);
            }
    WAITLG0();
    WAITVM4();   // P0 landed, P1 in flight
    SBAR();

    // ---- projection: OUT[64][512] = Y @ Wproj + b; 16 stages, 2-slot ring ----
    f32x4 Pacc[2][8];
#pragma unroll
    for (int a = 0; a < 2; ++a)
#pragma unroll
        for (int b = 0; b < 8; ++b) Pacc[a][b] = (f32x4){0.f, 0.f, 0.f, 0.f};
#pragma unroll 1
    for (int ps = 0; ps < 16; ++ps) {
        if (ps > 0) {
            SBAR();   // close ps-1 reads, free its slot
            if (ps < 15) {
                const char* sp = stream + ((size_t)(129 + ps) << 14) + tid * 16;
                char* dp = (((ps + 1) & 1) ? podd : peven) + woff;
                GLDS16(sp, dp); GLDS16(sp + 4096, dp + 4096);
                GLDS16(sp + 8192, dp + 8192); GLDS16(sp + 12288, dp + 12288);
                WAITVM4();
            } else WAITVM0();
            SBAR();
        }
        int t = ps & 7;
        const char* pb = (ps & 1) ? podd : peven;
        int r0 = 32 * wr + lm;
        bf16x8 af0 = *(const bf16x8*)(ysb + r0 * 512
                        + ((t * 64 + quad * 16) ^ ((r0 & 7) << 4)));
        bf16x8 af1 = *(const bf16x8*)(ysb + (r0 + 16) * 512
                        + ((t * 64 + quad * 16) ^ ((r0 & 7) << 4)));
        __builtin_amdgcn_s_setprio(1);
#pragma unroll
        for (int nt = 0; nt < 8; ++nt) {
            int rown = 128 * wc + 16 * nt + lm;
            bf16x8 b = *(const bf16x8*)(pb + rown * 64 + (swzB << 4));
            Pacc[0][nt] = MFMA16(af0, b, Pacc[0][nt]);
            Pacc[1][nt] = MFMA16(af1, b, Pacc[1][nt]);
        }
        __builtin_amdgcn_s_setprio(0);
        if (t == 7) {   // epilogue for p = ps>>3
            int p = ps >> 3;
#pragma unroll
            for (int nt = 0; nt < 8; ++nt) {
                int col = 256 * p + 128 * wc + 16 * nt + lm;
                float bv = f32m ? ((const float*)bp)[col] : bf2f(((const __hip_bfloat16*)bp)[col]);
#pragma unroll
                for (int mt = 0; mt < 2; ++mt)
#pragma unroll
                    for (int r = 0; r < 4; ++r) {
                        int row = m0 + 32 * wr + 16 * mt + quad * 4 + r;
                        float v = Pacc[mt][nt][r] + bv;
                        if (f32m) ((float*)outp)[(size_t)row * 512 + col] = v;
                        else ((__hip_bfloat16*)outp)[(size_t)row * 512 + col] = __float2bfloat16(v);
                    }
            }
            if (ps < 15) {
#pragma unroll
                for (int a = 0; a < 2; ++a)
#pragma unroll
                    for (int b = 0; b < 8; ++b) Pacc[a][b] = (f32x4){0.f, 0.f, 0.f, 0.f};
            }
        }
    }
}

extern "C" void kernel_launch(void* const* d_in, const int* in_sizes, int n_in,
                              void* d_out, int out_size, void* d_ws, size_t ws_size,
                              hipStream_t stream) {
    const void* x  = d_in[0];
    const void* wg = d_in[1];
    const void* w1 = d_in[2];
    const void* w2 = d_in[3];
    const void* wp = d_in[4];
    const void* bp = d_in[5];

    char* wstream = (char*)d_ws;   // 144 x 16384 = 2359296 B

    k_prep<<<576, 256, 0, stream>>>(w1, w2, wp, (const unsigned short*)x, wstream);
    k_moe<<<1024, 256, 66560, stream>>>(x, wg, wstream, bp, d_out);
}